// Round 3
// baseline (288.385 us; speedup 1.0000x reference)
//
#include <hip/hip_runtime.h>

// segment_sum: out[g, f] = sum over rows r with batch[r]==g of x[r, f]
// x: (200000, 256) f32; batch: (200000,) int32 SORTED; out: (512, 256) f32
//
// R3: balanced chunked pool. Timed window is dominated by ~240us of harness
// fills/restores (measured at 86% HBM peak); our portion's floor is 33us of
// x-streaming. Plan:
//   1. seg_bounds: start[g] = first row with batch[r] >= g; start[512] = n.
//   2. memsetAsync(out, 0)  (512 KB, capture-safe).
//   3. pool: 1024 blocks x 196 rows each (perfect static balance, 4 blocks/CU
//      all resident at t=0, 16 waves/CU). Each block walks the runs inside
//      its chunk via start[], streams each run branch-free (float4/lane,
//      unroll x4 = 4 loads in flight/wave), flushes per-run partials with
//      atomicAdd (~6 MB atomic traffic total, ~12 ops per out cell).

#define FEAT 256
#define F4   (FEAT / 4)   // 64 float4 per row == one wave-load per row
#define NSEG 512
#define NB   1024         // pool grid

__global__ void seg_bounds_kernel(const int* __restrict__ batch,
                                  int* __restrict__ start, int n) {
    int r = blockIdx.x * blockDim.x + threadIdx.x;
    if (r >= n) return;
    int cur = batch[r];
    if (r == 0) {
        for (int g = 0; g <= cur; ++g) start[g] = 0;
    } else {
        int prev = batch[r - 1];
        for (int g = prev + 1; g <= cur; ++g) start[g] = r;
    }
    if (r == n - 1) {
        for (int g = cur + 1; g <= NSEG; ++g) start[g] = n;
    }
}

__global__ __launch_bounds__(256) void GraphAddPooling_39539468927441_kernel(
    const float* __restrict__ x, const int* __restrict__ batch,
    const int* __restrict__ start, float* __restrict__ out,
    int n, int rows_per_block)
{
    const int lane = threadIdx.x & 63;
    const int wave = threadIdx.x >> 6;    // 0..3

    const int c0 = blockIdx.x * rows_per_block;
    if (c0 >= n) return;
    int c1 = c0 + rows_per_block;
    if (c1 > n) c1 = n;

    const float4* __restrict__ x4 = (const float4*)x;

    int g = batch[c0];                    // segment containing first row
    int r = c0;
    while (r < c1) {
        while (start[g + 1] <= r) ++g;    // skip empty segments
        int rend = start[g + 1];
        if (rend > c1) rend = c1;

        // Stream rows [r, rend): wave-interleaved, unroll x4.
        float4 a0 = make_float4(0.f, 0.f, 0.f, 0.f);
        float4 a1 = a0, a2 = a0, a3 = a0;
        int rr = r + wave;
        for (; rr + 12 < rend; rr += 16) {
            float4 v0 = x4[(size_t)rr        * F4 + lane];
            float4 v1 = x4[(size_t)(rr + 4)  * F4 + lane];
            float4 v2 = x4[(size_t)(rr + 8)  * F4 + lane];
            float4 v3 = x4[(size_t)(rr + 12) * F4 + lane];
            a0.x += v0.x; a0.y += v0.y; a0.z += v0.z; a0.w += v0.w;
            a1.x += v1.x; a1.y += v1.y; a1.z += v1.z; a1.w += v1.w;
            a2.x += v2.x; a2.y += v2.y; a2.z += v2.z; a2.w += v2.w;
            a3.x += v3.x; a3.y += v3.y; a3.z += v3.z; a3.w += v3.w;
        }
        for (; rr < rend; rr += 4) {
            float4 v = x4[(size_t)rr * F4 + lane];
            a0.x += v.x; a0.y += v.y; a0.z += v.z; a0.w += v.w;
        }
        a0.x += a1.x + a2.x + a3.x;
        a0.y += a1.y + a2.y + a3.y;
        a0.z += a1.z + a2.z + a3.z;
        a0.w += a1.w + a2.w + a3.w;

        float* o = out + (size_t)g * FEAT + lane * 4;
        atomicAdd(o + 0, a0.x);
        atomicAdd(o + 1, a0.y);
        atomicAdd(o + 2, a0.z);
        atomicAdd(o + 3, a0.w);

        r = rend;
    }
}

extern "C" void kernel_launch(void* const* d_in, const int* in_sizes, int n_in,
                              void* d_out, int out_size, void* d_ws, size_t ws_size,
                              hipStream_t stream) {
    const float* x     = (const float*)d_in[0];
    const int*   batch = (const int*)d_in[1];
    float*       out   = (float*)d_out;
    int*         start = (int*)d_ws;     // 513 ints, fully rewritten every call

    const int n_rows = in_sizes[1];      // 200000

    hipMemsetAsync(d_out, 0, (size_t)out_size * sizeof(float), stream);
    seg_bounds_kernel<<<(n_rows + 255) / 256, 256, 0, stream>>>(batch, start, n_rows);

    const int rows_per_block = (n_rows + NB - 1) / NB;
    GraphAddPooling_39539468927441_kernel<<<NB, 256, 0, stream>>>(
        x, batch, start, out, n_rows, rows_per_block);
}